// Round 9
// baseline (733.452 us; speedup 1.0000x reference)
//
#include <hip/hip_runtime.h>
#include <hip/hip_bf16.h>
#include <stdint.h>

#define DEVI __device__ __forceinline__

typedef unsigned short u16;
typedef __attribute__((ext_vector_type(8))) short short8;
typedef __attribute__((ext_vector_type(4))) float f32x4;
typedef __attribute__((ext_vector_type(16))) float f32x16;

DEVI u16 f2bf(float f) {
  union { float f; uint32_t u; } v; v.f = f;
  return (u16)((v.u + 0x7fffu + ((v.u >> 16) & 1u)) >> 16);
}
// cheap activations: v_rcp (1 ulp) instead of the 9-inst correctly-rounded div.
DEVI float tanh_c(float x) {
  float e = __expf(x + x);
  float r = __builtin_amdgcn_rcpf(e + 1.0f);
  return __builtin_fmaf(-2.0f, r, 1.0f);
}
DEVI float sigm(float x) { return __builtin_amdgcn_rcpf(1.0f + __expf(-x)); }
// two tanh -> packed bf16x2 (hardware v_cvt_pk_bf16_f32, RNE)
DEVI uint32_t tj2(float a, float b) {
  float ea = __expf(a + a), eb = __expf(b + b);
  float ta = __builtin_fmaf(-2.0f, __builtin_amdgcn_rcpf(ea + 1.0f), 1.0f);
  float tb = __builtin_fmaf(-2.0f, __builtin_amdgcn_rcpf(eb + 1.0f), 1.0f);
  union { __hip_bfloat162 h; uint32_t u; } cv;
  cv.h = __float22bfloat162_rn(make_float2(ta, tb));
  return cv.u;
}

// ---------------------------------------------------------------- prep
__global__ void prep_kernel(
    const float* __restrict__ W_ih0, const float* __restrict__ W_hh0,
    const float* __restrict__ W_ih1, const float* __restrict__ W_hh1,
    const float* __restrict__ W_enc, const float* __restrict__ W_dec,
    const float* __restrict__ W_out, const float* __restrict__ embed,
    const float* __restrict__ hs_pad,
    const float* __restrict__ b_ih0, const float* __restrict__ b_hh0,
    const float* __restrict__ b_ih1, const float* __restrict__ b_hh1,
    const float* __restrict__ b_out,
    u16* __restrict__ Wih0b, u16* __restrict__ Whh0b,
    u16* __restrict__ Wih1b, u16* __restrict__ Whh1b,
    u16* __restrict__ Wencb, u16* __restrict__ Wdecb,
    u16* __restrict__ embedb, u16* __restrict__ hsb,
    u16* __restrict__ Wshufb,
    float* __restrict__ bsum0, float* __restrict__ bsum1, float* __restrict__ boutp)
{
  const int c1 = 1048576, c2 = 2097152, c3 = 3145728, c4 = 4194304;
  const int c5 = 4456448, c6 = 4718592, c7 = 5025792, c8 = 6664192;
  const int c9 = 6991872, c10 = 6993920, c11 = 6995968, c12 = 6996608;
  for (int i = blockIdx.x * blockDim.x + threadIdx.x; i < c12; i += gridDim.x * blockDim.x) {
    if (i < c1)       Wih0b[i]      = f2bf(W_ih0[i]);
    else if (i < c2)  Whh0b[i - c1] = f2bf(W_hh0[i - c1]);
    else if (i < c3)  Wih1b[i - c2] = f2bf(W_ih1[i - c2]);
    else if (i < c4)  Whh1b[i - c3] = f2bf(W_hh1[i - c3]);
    else if (i < c5)  Wencb[i - c4] = f2bf(W_enc[i - c4]);
    else if (i < c6)  Wdecb[i - c5] = f2bf(W_dec[i - c5]);
    else if (i < c7)  embedb[i - c6] = f2bf(embed[i - c6]);
    else if (i < c8)  hsb[i - c7]   = f2bf(hs_pad[i - c7]);
    else if (i < c9) {
      // W_out pre-shuffled for 32x32x16 B-fragments: [32 kc][20 tile][64 lane][8]
      int e = i - c8;
      int kc = e / 10240, r = e % 10240;
      int tile = r >> 9, r2 = r & 511;
      int lane = r2 >> 3, ii = r2 & 7;
      int n = tile * 32 + (lane & 31);
      int k = kc * 16 + ((lane >> 5) << 3) + ii;
      Wshufb[e] = (n < 600) ? f2bf(W_out[n * 512 + k]) : (u16)0;
    }
    else if (i < c10) { int n = i - c9;  bsum0[n] = b_ih0[n] + b_hh0[n]; }
    else if (i < c11) { int n = i - c10; bsum1[n] = b_ih1[n] + b_hh1[n]; }
    else              { int n = i - c11; boutp[n] = (n < 600) ? b_out[n] : 0.0f; }
  }
}

// ------------------------------------------------- generic 64x64 MFMA GEMM
__global__ __launch_bounds__(256) void gemm_bf16(
    const u16* __restrict__ A, const u16* __restrict__ B,
    const int* __restrict__ ys, const float* __restrict__ bias,
    float* __restrict__ out, int N, int mode)
{
  int tid = threadIdx.x, wv = tid >> 6, l = tid & 63;
  int m0 = blockIdx.x * 64, n0 = blockIdx.y * 64;
  int row = m0 + wv * 16 + (l & 15);
  const u16* arow;
  if (mode == 1) { int uu = row >> 4, bb = row & 15; arow = A + (size_t)ys[bb * 64 + uu] * 512; }
  else           arow = A + (size_t)row * 512;
  int kof = (l >> 4) * 8;
  arow += kof;
  const u16* br = B + (size_t)(n0 + (l & 15)) * 512 + kof;
  f32x4 a0 = {0.f,0.f,0.f,0.f}, a1 = a0, a2 = a0, a3 = a0;
  for (int kk = 0; kk < 512; kk += 32) {
    short8 av = *(const short8*)(arow + kk);
    short8 b0 = *(const short8*)(br + kk);
    short8 b1 = *(const short8*)(br + 8192 + kk);
    short8 b2 = *(const short8*)(br + 16384 + kk);
    short8 b3 = *(const short8*)(br + 24576 + kk);
    a0 = __builtin_amdgcn_mfma_f32_16x16x32_bf16(av, b0, a0, 0, 0, 0);
    a1 = __builtin_amdgcn_mfma_f32_16x16x32_bf16(av, b1, a1, 0, 0, 0);
    a2 = __builtin_amdgcn_mfma_f32_16x16x32_bf16(av, b2, a2, 0, 0, 0);
    a3 = __builtin_amdgcn_mfma_f32_16x16x32_bf16(av, b3, a3, 0, 0, 0);
  }
  int col = l & 15, rb = m0 + wv * 16 + (l >> 4) * 4;
  f32x4 accs[4] = {a0, a1, a2, a3};
#pragma unroll
  for (int g = 0; g < 4; ++g) {
    int n = n0 + g * 16 + col;
    float bs = bias ? bias[n] : 0.0f;
#pragma unroll
    for (int i2 = 0; i2 < 4; ++i2)
      out[(size_t)(rb + i2) * N + n] = accs[g][i2] + bs;
  }
}

// ---------------------------------------------------------------- LSTM
// Decoupled chains: 32 L0 WGs (16 units) + 64 L1 WGs (8 units). Ring depth 8.
// All cross-WG h/flag traffic = agent-scope atomics (coherent point). RELAXED
// polls + one acquire fence on exit; producer: s_waitcnt vmcnt(0) + relaxed store.
#define L0WG 32
#define NWGT 96

DEVI short8 ald16(const u16* p) {
  union { unsigned long long q[2]; short8 v; } u;
  u.q[0] = __hip_atomic_load((unsigned long long*)p,       __ATOMIC_RELAXED, __HIP_MEMORY_SCOPE_AGENT);
  u.q[1] = __hip_atomic_load((unsigned long long*)(p + 4), __ATOMIC_RELAXED, __HIP_MEMORY_SCOPE_AGENT);
  return u.v;
}
DEVI void waitflags(const int* f0, const int* f1, int n0, int n1) {
  if (threadIdx.x < 64) {
    int l = threadIdx.x;
    for (;;) {
      int a = __hip_atomic_load((int*)(f0 + (l & 31) * 16), __ATOMIC_RELAXED, __HIP_MEMORY_SCOPE_AGENT);
      int b = __hip_atomic_load((int*)(f1 + l * 16),        __ATOMIC_RELAXED, __HIP_MEMORY_SCOPE_AGENT);
      if (__all(a >= n0 && b >= n1)) break;
      __builtin_amdgcn_s_sleep(1);
    }
    __builtin_amdgcn_fence(__ATOMIC_ACQUIRE, "agent");  // pin h-loads below poll
  }
  __syncthreads();
}
DEVI void postflag(int* slot, int val) {
  __syncthreads();
  if (threadIdx.x == 0) {
    asm volatile("s_waitcnt vmcnt(0)" ::: "memory");    // h-stores ack'd at L3
    __hip_atomic_store(slot, val, __ATOMIC_RELAXED, __HIP_MEMORY_SCOPE_AGENT);
  }
}
DEVI const u16* haddr(const u16* base, int slot, int k, int b) {
  return base + slot * 8192 + (k >> 4) * 256 + b * 16 + (k & 15);
}
DEVI void hstore(u16* base, int idx, u16 mine, int tid) {
  int other = __shfl_xor((int)mine, 1);
  if (!(tid & 1)) {
    uint32_t pkv = (uint32_t)mine | (((uint32_t)other & 0xffffu) << 16);
    __hip_atomic_store((uint32_t*)(base + idx), pkv, __ATOMIC_RELAXED, __HIP_MEMORY_SCOPE_AGENT);
  }
}

__global__ __launch_bounds__(256) void lstm_kernel(
    const float* __restrict__ Xg0,                 // [64][16][2048] (x@Wih0^T + bsum0)
    const u16* __restrict__ Whh0, const u16* __restrict__ Wih1, const u16* __restrict__ Whh1,
    const float* __restrict__ bsum1,
    u16* __restrict__ h0b, u16* __restrict__ h1b,  // [8][32][16][16] rings
    u16* __restrict__ Hdec,                        // [64][16][512] bf16
    int* __restrict__ flags0, int* __restrict__ flags1)
{
  __shared__ float red[16][256];
  const int bid = blockIdx.x, tid = threadIdx.x;
  const int wv = tid >> 6, l = tid & 63;
  const int lb = l & 15, kof = (l >> 4) * 8;
  const int drb = (l >> 4) * 4;

  if (bid < L0WG) {
    // ---------------- layer 0: units [16*bid, +16)
    const int be = tid >> 4, je = tid & 15, jg = (bid << 4) + je;
    short8 breg[16];
#pragma unroll
    for (int g = 0; g < 4; ++g) {
      const u16* bp = Whh0 + (size_t)(g * 512 + bid * 16 + lb) * 512 + wv * 128 + kof;
#pragma unroll
      for (int ks = 0; ks < 4; ++ks)
        breg[g * 4 + ks] = *(const short8*)(bp + ks * 32);
    }
    float c0 = 0.f;
    for (int t = 0; t < 64; ++t) {
      // prefetch Xg0 before the flag wait
      const float* xg = Xg0 + (size_t)((t << 4) + be) * 2048 + jg;
      float x0 = xg[0], x1 = xg[512], x2 = xg[1024], x3 = xg[1536];
      waitflags(flags0, flags1, t, (t > 7) ? (t - 7) : 0);
      const int rs = (t + 7) & 7;
      f32x4 g0 = {0.f,0.f,0.f,0.f}, g1 = g0, g2 = g0, g3 = g0;
#pragma unroll
      for (int ks = 0; ks < 4; ++ks) {
        int kk = wv * 128 + ks * 32 + kof;
        short8 av = ald16(haddr(h0b, rs, kk, lb));
        g0 = __builtin_amdgcn_mfma_f32_16x16x32_bf16(av, breg[0 * 4 + ks], g0, 0, 0, 0);
        g1 = __builtin_amdgcn_mfma_f32_16x16x32_bf16(av, breg[1 * 4 + ks], g1, 0, 0, 0);
        g2 = __builtin_amdgcn_mfma_f32_16x16x32_bf16(av, breg[2 * 4 + ks], g2, 0, 0, 0);
        g3 = __builtin_amdgcn_mfma_f32_16x16x32_bf16(av, breg[3 * 4 + ks], g3, 0, 0, 0);
      }
      f32x4 gs[4] = {g0, g1, g2, g3};
#pragma unroll
      for (int g = 0; g < 4; ++g)
#pragma unroll
        for (int i2 = 0; i2 < 4; ++i2)
          red[wv * 4 + g][(drb + i2) * 16 + lb] = gs[g][i2];
      __syncthreads();
      {
        float s0 = 0, s1 = 0, s2 = 0, s3 = 0;
#pragma unroll
        for (int v2 = 0; v2 < 4; ++v2) {
          s0 += red[v2 * 4 + 0][be * 16 + je]; s1 += red[v2 * 4 + 1][be * 16 + je];
          s2 += red[v2 * 4 + 2][be * 16 + je]; s3 += red[v2 * 4 + 3][be * 16 + je];
        }
        float gi = s0 + x0, gf = s1 + x1, gg = s2 + x2, go = s3 + x3;
        float I = sigm(gi), F = sigm(gf), G = tanh_c(gg), O = sigm(go);
        c0 = F * c0 + I * G;
        float h0 = O * tanh_c(c0);
        hstore(h0b, ((t & 7) * 32 + bid) * 256 + (tid & ~1), f2bf(h0), tid);
      }
      postflag(flags0 + bid * 16, t + 1);
    }
  } else {
    // ---------------- layer 1: units [8v, +8), v = bid-32
    const int v = bid - L0WG;
    const u16* base0 = (wv < 2) ? Wih1 : Whh1;
    const int kbase = (wv & 1) * 256;
    short8 breg[16];
#pragma unroll
    for (int tt = 0; tt < 2; ++tt) {
      int c = tt * 16 + lb, gate = c >> 3, du = c & 7;
      const u16* bp = base0 + (size_t)(gate * 512 + v * 8 + du) * 512 + kbase + kof;
#pragma unroll
      for (int ks = 0; ks < 8; ++ks)
        breg[tt * 8 + ks] = *(const short8*)(bp + ks * 32);
    }
    float bs0 = 0, bs1 = 0, bs2 = 0, bs3 = 0, c1 = 0.f;
    if (tid < 128) {
      int du = tid & 7, ju = v * 8 + du;
      bs0 = bsum1[ju]; bs1 = bsum1[512 + ju]; bs2 = bsum1[1024 + ju]; bs3 = bsum1[1536 + ju];
    }
    for (int t = 0; t < 64; ++t) {
      waitflags(flags0, flags1, t + 1, t);
      const u16* hsrc = (wv < 2) ? (h0b + (t & 7) * 8192) : (h1b + ((t + 7) & 7) * 8192);
      f32x4 g0 = {0.f,0.f,0.f,0.f}, g1 = g0;
#pragma unroll
      for (int ks = 0; ks < 8; ++ks) {
        int kk = kbase + ks * 32 + kof;
        short8 av = ald16(hsrc + (kk >> 4) * 256 + lb * 16 + (kk & 15));
        g0 = __builtin_amdgcn_mfma_f32_16x16x32_bf16(av, breg[0 * 8 + ks], g0, 0, 0, 0);
        g1 = __builtin_amdgcn_mfma_f32_16x16x32_bf16(av, breg[1 * 8 + ks], g1, 0, 0, 0);
      }
#pragma unroll
      for (int i2 = 0; i2 < 4; ++i2) {
        red[wv * 2 + 0][(drb + i2) * 16 + lb] = g0[i2];
        red[wv * 2 + 1][(drb + i2) * 16 + lb] = g1[i2];
      }
      __syncthreads();
      u16 hb = 0; int be = 0, ju = 0;
      if (tid < 128) {
        be = tid >> 3; int du = tid & 7; ju = v * 8 + du;
        float sg[4] = {bs0, bs1, bs2, bs3};
#pragma unroll
        for (int g = 0; g < 4; ++g) {
          int c = g * 8 + du, tt = c >> 4, cc = c & 15;
          float acc = 0.f;
#pragma unroll
          for (int w2 = 0; w2 < 4; ++w2) acc += red[w2 * 2 + tt][be * 16 + cc];
          sg[g] += acc;
        }
        float I = sigm(sg[0]), F = sigm(sg[1]), G = tanh_c(sg[2]), O = sigm(sg[3]);
        c1 = F * c1 + I * G;
        float h1v = O * tanh_c(c1);
        hb = f2bf(h1v);
        int idx = ((t & 7) * 32 + (ju >> 4)) * 256 + be * 16 + (ju & 15);
        hstore(h1b, idx & ~1, hb, tid);
      }
      postflag(flags1 + v * 16, t + 1);
      if (tid < 128) Hdec[(size_t)((t << 4) + be) * 512 + ju] = hb;  // off critical path
    }
  }
}

// ---------------------------------------------------------------- joint
// out[b][t][u][n] = tanh(enc_p[b,t,:]+dec_p[u,b,:]) @ W_out^T + b_out
// 256 thr (2M x 2N waves), M-tile 128 rows (8t x 16u), N-tile 320 (nh half).
// Each wave: 20 MFMA per chunk vs 14 ds_read_b128 (was 10 vs 12 in r8 --
// the inner loop was LDS-read-bound). W dbuf 2x20KB + z dbuf 2x8KB = 56 KB
// -> 2 WGs/CU. One barrier per chunk; next-chunk loads issued before MFMAs.
__global__ __launch_bounds__(256) void joint_kernel(
    const float* __restrict__ enc_p,   // [16*200][512]
    const float* __restrict__ dec_p,   // [64*16][512]  row = u*16+b
    const u16* __restrict__ Wshuf,     // [32 kc][20 tile][64 lane][8] bf16
    const float* __restrict__ boutp,   // [640]
    float* __restrict__ out)
{
  __shared__ int4 wlds[2][1280];  // 2 x 20KB: W chunk (2 kc x 10 tiles x 64 lanes)
  __shared__ int4 zlds[2][512];   // 2 x 8KB:  z chunk 128 rows x 32 k, frag-shuffled
  int bid = blockIdx.x;
  // grid 3200: b(16) x tb(25) x ub(4) x nh(2)
  int b = bid / 200, rem = bid % 200;
  int tb = rem / 8, rem2 = rem % 8;
  int ub = rem2 >> 1, nh = rem2 & 1;
  int tid = threadIdx.x, wv = tid >> 6, l = tid & 63;
  int mv = wv >> 1, nv = wv & 1;     // 2M x 2N
  int ln31 = l & 31, lh = l >> 5;
  const int tile0 = nv * 5;
  f32x16 acc0[5], acc1[5];
#pragma unroll
  for (int j = 0; j < 5; ++j) {
    float bv = boutp[nh * 320 + (tile0 + j) * 32 + ln31];
#pragma unroll
    for (int g = 0; g < 16; ++g) { acc0[j][g] = bv; acc1[j][g] = bv; }
  }
  // z-build: thread (zr, zg) owns row zr, k-groups {8*zg, 16+8*zg} of each chunk
  int zr = tid & 127, zg = tid >> 7;
  const float* er = enc_p + (size_t)(b * 200 + tb * 8 + (zr >> 4)) * 512 + zg * 8;
  const float* dr = dec_p + (size_t)((ub * 16 + (zr & 15)) * 16 + b) * 512 + zg * 8;
  const int zslotA = (zr >> 5) * 64 + (zg << 5) + (zr & 31);       // ks=0 frags
  const int zslotB = zslotA + 256;                                  // ks=1 frags
  const int4* gW = (const int4*)Wshuf;
  const int nhof = nh * 640;
  const int L0 = tid, L1 = 256 + tid, L2 = 512 + tid + ((tid >= 128) ? 640 : 0),
            L3 = 1408 + tid, L4 = 1664 + tid;
  const int S2 = 512 + tid;  // LDS slot for the q=2 load

  // ---- prologue: W(0) -> wlds[0], z(0) -> zlds[0]
  {
    int4 w0 = gW[nhof + L0], w1 = gW[nhof + L1], w2 = gW[nhof + L2],
         w3 = gW[nhof + L3], w4 = gW[nhof + L4];
    float4 eA = *(const float4*)(er),      eB = *(const float4*)(er + 4);
    float4 eC = *(const float4*)(er + 16), eD = *(const float4*)(er + 20);
    float4 dA = *(const float4*)(dr),      dB = *(const float4*)(dr + 4);
    float4 dC = *(const float4*)(dr + 16), dD = *(const float4*)(dr + 20);
    int4 pkA, pkB;
    pkA.x = (int)tj2(eA.x + dA.x, eA.y + dA.y);
    pkA.y = (int)tj2(eA.z + dA.z, eA.w + dA.w);
    pkA.z = (int)tj2(eB.x + dB.x, eB.y + dB.y);
    pkA.w = (int)tj2(eB.z + dB.z, eB.w + dB.w);
    pkB.x = (int)tj2(eC.x + dC.x, eC.y + dC.y);
    pkB.y = (int)tj2(eC.z + dC.z, eC.w + dC.w);
    pkB.z = (int)tj2(eD.x + dD.x, eD.y + dD.y);
    pkB.w = (int)tj2(eD.z + dD.z, eD.w + dD.w);
    zlds[0][zslotA] = pkA;
    zlds[0][zslotB] = pkB;
    wlds[0][tid] = w0; wlds[0][256 + tid] = w1; wlds[0][S2] = w2;
    wlds[0][768 + tid] = w3; wlds[0][1024 + tid] = w4;
    __syncthreads();
  }

  for (int c = 0; c < 16; ++c) {
    const int cur = c & 1, nxt = cur ^ 1;
    const bool pf = (c < 15);
    int4 w0, w1, w2, w3, w4;
    float4 eA, eB, eC, eD, dA, dB, dC, dD;
    if (pf) {
      // issue next-chunk loads early; the 20 MFMAs below hide the L2 latency
      const int cb = (c + 1) * 2560 + nhof;
      w0 = gW[cb + L0]; w1 = gW[cb + L1]; w2 = gW[cb + L2];
      w3 = gW[cb + L3]; w4 = gW[cb + L4];
      int k0 = (c + 1) * 32;
      eA = *(const float4*)(er + k0);      eB = *(const float4*)(er + k0 + 4);
      eC = *(const float4*)(er + k0 + 16); eD = *(const float4*)(er + k0 + 20);
      dA = *(const float4*)(dr + k0);      dB = *(const float4*)(dr + k0 + 4);
      dC = *(const float4*)(dr + k0 + 16); dD = *(const float4*)(dr + k0 + 20);
    }
    // MFMA on chunk c: 2 A-frags x 5 W-tiles x 2 ks = 20 MFMA / 14 ds_read
#pragma unroll
    for (int ks = 0; ks < 2; ++ks) {
      short8 a0 = *(const short8*)&zlds[cur][(ks * 4 + 2 * mv + 0) * 64 + l];
      short8 a1 = *(const short8*)&zlds[cur][(ks * 4 + 2 * mv + 1) * 64 + l];
#pragma unroll
      for (int j = 0; j < 5; ++j) {
        short8 bw = *(const short8*)&wlds[cur][ks * 640 + (tile0 + j) * 64 + l];
        acc0[j] = __builtin_amdgcn_mfma_f32_32x32x16_bf16(a0, bw, acc0[j], 0, 0, 0);
        acc1[j] = __builtin_amdgcn_mfma_f32_32x32x16_bf16(a1, bw, acc1[j], 0, 0, 0);
      }
    }
    if (pf) {
      // write next chunk into the other buffers, then ONE barrier
      wlds[nxt][tid] = w0; wlds[nxt][256 + tid] = w1; wlds[nxt][S2] = w2;
      wlds[nxt][768 + tid] = w3; wlds[nxt][1024 + tid] = w4;
      int4 pkA, pkB;
      pkA.x = (int)tj2(eA.x + dA.x, eA.y + dA.y);
      pkA.y = (int)tj2(eA.z + dA.z, eA.w + dA.w);
      pkA.z = (int)tj2(eB.x + dB.x, eB.y + dB.y);
      pkA.w = (int)tj2(eB.z + dB.z, eB.w + dB.w);
      pkB.x = (int)tj2(eC.x + dC.x, eC.y + dC.y);
      pkB.y = (int)tj2(eC.z + dC.z, eC.w + dC.w);
      pkB.z = (int)tj2(eD.x + dD.x, eD.y + dD.y);
      pkB.w = (int)tj2(eD.z + dD.z, eD.w + dD.w);
      zlds[nxt][zslotA] = pkA;
      zlds[nxt][zslotB] = pkB;
    }
    __syncthreads();
  }

  // epilogue: D[row][col]: col = lane&31, row = (g&3) + 8*(g>>2) + 4*(lane>>5)
#pragma unroll
  for (int j = 0; j < 5; ++j) {
    int n = nh * 320 + (tile0 + j) * 32 + ln31;
    if (n < 600) {
      int rb0 = (2 * mv) * 32 + 4 * lh;
#pragma unroll
      for (int g = 0; g < 16; ++g) {
        int r = rb0 + (g & 3) + ((g >> 2) << 3);
        int tt = tb * 8 + (r >> 4), uu = ub * 16 + (r & 15);
        out[(size_t)((b * 200 + tt) * 64 + uu) * 600 + n] = acc0[j][g];
      }
      int rb1 = (2 * mv + 1) * 32 + 4 * lh;
#pragma unroll
      for (int g = 0; g < 16; ++g) {
        int r = rb1 + (g & 3) + ((g >> 2) << 3);
        int tt = tb * 8 + (r >> 4), uu = ub * 16 + (r & 15);
        out[(size_t)((b * 200 + tt) * 64 + uu) * 600 + n] = acc1[j][g];
      }
    }
  }
}

// ---------------------------------------------------------------- host
extern "C" void kernel_launch(void* const* d_in, const int* in_sizes, int n_in,
                              void* d_out, int out_size, void* d_ws, size_t ws_size,
                              hipStream_t stream) {
  const float* hs_pad = (const float*)d_in[0];
  const int*   ys     = (const int*)d_in[1];
  const float* embed  = (const float*)d_in[2];
  const float* W_ih0  = (const float*)d_in[3];
  const float* W_hh0  = (const float*)d_in[4];
  const float* b_ih0  = (const float*)d_in[5];
  const float* b_hh0  = (const float*)d_in[6];
  const float* W_ih1  = (const float*)d_in[7];
  const float* W_hh1  = (const float*)d_in[8];
  const float* b_ih1  = (const float*)d_in[9];
  const float* b_hh1  = (const float*)d_in[10];
  const float* W_enc  = (const float*)d_in[11];
  const float* b_enc  = (const float*)d_in[12];
  const float* W_dec  = (const float*)d_in[13];
  const float* W_out  = (const float*)d_in[14];
  const float* b_out  = (const float*)d_in[15];
  float* out = (float*)d_out;

  uint8_t* ws = (uint8_t*)d_ws;
  size_t off = 0;
  auto alloc = [&](size_t bytes) -> void* {
    void* p = ws + off;
    off = (off + bytes + 255) & ~(size_t)255;
    return p;
  };
  int* flags0   = (int*)alloc(2048);                     // 32 slots x 64B
  int* flags1   = (int*)alloc(4096);                     // 64 slots x 64B
  u16* h0buf    = (u16*)alloc(8 * 32 * 256 * 2);         // 128 KB ring (8 slots)
  u16* h1buf    = (u16*)alloc(8 * 32 * 256 * 2);         // 128 KB ring
  u16* Hdec     = (u16*)alloc(64 * 16 * 512 * 2);        // 1 MB
  float* Xg0    = (float*)alloc(1024 * 2048 * 4);        // 8 MB
  float* enc_p  = (float*)alloc(3200 * 512 * 4);         // 6.5 MB
  float* dec_p  = (float*)alloc(1024 * 512 * 4);         // 2 MB
  u16* Wih0b    = (u16*)alloc(2048 * 512 * 2);
  u16* Whh0b    = (u16*)alloc(2048 * 512 * 2);
  u16* Wih1b    = (u16*)alloc(2048 * 512 * 2);
  u16* Whh1b    = (u16*)alloc(2048 * 512 * 2);
  u16* Wencb    = (u16*)alloc(512 * 512 * 2);
  u16* Wdecb    = (u16*)alloc(512 * 512 * 2);
  u16* embedb   = (u16*)alloc(600 * 512 * 2);
  u16* hsb      = (u16*)alloc(3200 * 512 * 2);
  u16* Wshufb   = (u16*)alloc(32 * 20 * 64 * 8 * 2);
  float* bsum0  = (float*)alloc(2048 * 4);
  float* bsum1  = (float*)alloc(2048 * 4);
  float* boutp  = (float*)alloc(640 * 4);

  // zero flags + h rings (contiguous: 2048 + 4096 + 128K + 128K)
  (void)hipMemsetAsync(d_ws, 0, 2048 + 4096 + 131072 + 131072, stream);

  prep_kernel<<<2048, 256, 0, stream>>>(
      W_ih0, W_hh0, W_ih1, W_hh1, W_enc, W_dec, W_out, embed, hs_pad,
      b_ih0, b_hh0, b_ih1, b_hh1, b_out,
      Wih0b, Whh0b, Wih1b, Whh1b, Wencb, Wdecb, embedb, hsb, Wshufb,
      bsum0, bsum1, boutp);

  // Xg0 = embed[ys] @ W_ih0^T + (b_ih0 + b_hh0), rows m = u*16+b
  dim3 g1(16, 32);
  gemm_bf16<<<g1, 256, 0, stream>>>(embedb, Wih0b, ys, bsum0, Xg0, 2048, 1);
  // enc_p = hs @ W_enc^T + b_enc
  dim3 g2(50, 8);
  gemm_bf16<<<g2, 256, 0, stream>>>(hsb, Wencb, nullptr, b_enc, enc_p, 512, 0);
  // sequential 2-layer LSTM (decoupled chains, coherent atomics, light sync)
  lstm_kernel<<<NWGT, 256, 0, stream>>>(Xg0, Whh0b, Wih1b, Whh1b, bsum1,
                                        h0buf, h1buf, Hdec, flags0, flags1);
  // dec_p = Hdec @ W_dec^T
  dim3 g3(16, 8);
  gemm_bf16<<<g3, 256, 0, stream>>>(Hdec, Wdecb, nullptr, nullptr, dec_p, 512, 0);
  // big fused joint (M=128 x N=320 tiles)
  joint_kernel<<<3200, 256, 0, stream>>>(enc_p, dec_p, Wshufb, boutp, out);
}

// Round 10
// 672.332 us; speedup vs baseline: 1.0909x; 1.0909x over previous
//
#include <hip/hip_runtime.h>
#include <hip/hip_bf16.h>
#include <stdint.h>

#define DEVI __device__ __forceinline__

typedef unsigned short u16;
typedef __attribute__((ext_vector_type(8))) short short8;
typedef __attribute__((ext_vector_type(4))) float f32x4;
typedef __attribute__((ext_vector_type(16))) float f32x16;

DEVI u16 f2bf(float f) {
  union { float f; uint32_t u; } v; v.f = f;
  return (u16)((v.u + 0x7fffu + ((v.u >> 16) & 1u)) >> 16);
}
// cheap activations: v_rcp (1 ulp) instead of the 9-inst correctly-rounded div.
DEVI float tanh_c(float x) {
  float e = __expf(x + x);
  float r = __builtin_amdgcn_rcpf(e + 1.0f);
  return __builtin_fmaf(-2.0f, r, 1.0f);
}
DEVI float sigm(float x) { return __builtin_amdgcn_rcpf(1.0f + __expf(-x)); }
// two tanh -> packed bf16x2 (hardware v_cvt_pk_bf16_f32, RNE)
DEVI uint32_t tj2(float a, float b) {
  float ea = __expf(a + a), eb = __expf(b + b);
  float ta = __builtin_fmaf(-2.0f, __builtin_amdgcn_rcpf(ea + 1.0f), 1.0f);
  float tb = __builtin_fmaf(-2.0f, __builtin_amdgcn_rcpf(eb + 1.0f), 1.0f);
  union { __hip_bfloat162 h; uint32_t u; } cv;
  cv.h = __float22bfloat162_rn(make_float2(ta, tb));
  return cv.u;
}
// async global->LDS DMA, 16B/lane. LDS dest: wave-uniform base + lane*16.
DEVI void gl16(const int4* g, int4* l) {
  __builtin_amdgcn_global_load_lds(
      (const __attribute__((address_space(1))) uint32_t*)g,
      (__attribute__((address_space(3))) uint32_t*)l, 16, 0, 0);
}

// ---------------------------------------------------------------- prep
__global__ void prep_kernel(
    const float* __restrict__ W_ih0, const float* __restrict__ W_hh0,
    const float* __restrict__ W_ih1, const float* __restrict__ W_hh1,
    const float* __restrict__ W_enc, const float* __restrict__ W_dec,
    const float* __restrict__ W_out, const float* __restrict__ embed,
    const float* __restrict__ hs_pad,
    const float* __restrict__ b_ih0, const float* __restrict__ b_hh0,
    const float* __restrict__ b_ih1, const float* __restrict__ b_hh1,
    const float* __restrict__ b_out,
    u16* __restrict__ Wih0b, u16* __restrict__ Whh0b,
    u16* __restrict__ Wih1b, u16* __restrict__ Whh1b,
    u16* __restrict__ Wencb, u16* __restrict__ Wdecb,
    u16* __restrict__ embedb, u16* __restrict__ hsb,
    u16* __restrict__ Wshufb,
    float* __restrict__ bsum0, float* __restrict__ bsum1, float* __restrict__ boutp)
{
  const int c1 = 1048576, c2 = 2097152, c3 = 3145728, c4 = 4194304;
  const int c5 = 4456448, c6 = 4718592, c7 = 5025792, c8 = 6664192;
  const int c9 = 6991872, c10 = 6993920, c11 = 6995968, c12 = 6996608;
  for (int i = blockIdx.x * blockDim.x + threadIdx.x; i < c12; i += gridDim.x * blockDim.x) {
    if (i < c1)       Wih0b[i]      = f2bf(W_ih0[i]);
    else if (i < c2)  Whh0b[i - c1] = f2bf(W_hh0[i - c1]);
    else if (i < c3)  Wih1b[i - c2] = f2bf(W_ih1[i - c2]);
    else if (i < c4)  Whh1b[i - c3] = f2bf(W_hh1[i - c3]);
    else if (i < c5)  Wencb[i - c4] = f2bf(W_enc[i - c4]);
    else if (i < c6)  Wdecb[i - c5] = f2bf(W_dec[i - c5]);
    else if (i < c7)  embedb[i - c6] = f2bf(embed[i - c6]);
    else if (i < c8)  hsb[i - c7]   = f2bf(hs_pad[i - c7]);
    else if (i < c9) {
      // W_out pre-shuffled for 32x32x16 B-fragments: [32 kc][20 tile][64 lane][8]
      int e = i - c8;
      int kc = e / 10240, r = e % 10240;
      int tile = r >> 9, r2 = r & 511;
      int lane = r2 >> 3, ii = r2 & 7;
      int n = tile * 32 + (lane & 31);
      int k = kc * 16 + ((lane >> 5) << 3) + ii;
      Wshufb[e] = (n < 600) ? f2bf(W_out[n * 512 + k]) : (u16)0;
    }
    else if (i < c10) { int n = i - c9;  bsum0[n] = b_ih0[n] + b_hh0[n]; }
    else if (i < c11) { int n = i - c10; bsum1[n] = b_ih1[n] + b_hh1[n]; }
    else              { int n = i - c11; boutp[n] = (n < 600) ? b_out[n] : 0.0f; }
  }
}

// ------------------------------------------------- generic 64x64 MFMA GEMM
__global__ __launch_bounds__(256) void gemm_bf16(
    const u16* __restrict__ A, const u16* __restrict__ B,
    const int* __restrict__ ys, const float* __restrict__ bias,
    float* __restrict__ out, int N, int mode)
{
  int tid = threadIdx.x, wv = tid >> 6, l = tid & 63;
  int m0 = blockIdx.x * 64, n0 = blockIdx.y * 64;
  int row = m0 + wv * 16 + (l & 15);
  const u16* arow;
  if (mode == 1) { int uu = row >> 4, bb = row & 15; arow = A + (size_t)ys[bb * 64 + uu] * 512; }
  else           arow = A + (size_t)row * 512;
  int kof = (l >> 4) * 8;
  arow += kof;
  const u16* br = B + (size_t)(n0 + (l & 15)) * 512 + kof;
  f32x4 a0 = {0.f,0.f,0.f,0.f}, a1 = a0, a2 = a0, a3 = a0;
  for (int kk = 0; kk < 512; kk += 32) {
    short8 av = *(const short8*)(arow + kk);
    short8 b0 = *(const short8*)(br + kk);
    short8 b1 = *(const short8*)(br + 8192 + kk);
    short8 b2 = *(const short8*)(br + 16384 + kk);
    short8 b3 = *(const short8*)(br + 24576 + kk);
    a0 = __builtin_amdgcn_mfma_f32_16x16x32_bf16(av, b0, a0, 0, 0, 0);
    a1 = __builtin_amdgcn_mfma_f32_16x16x32_bf16(av, b1, a1, 0, 0, 0);
    a2 = __builtin_amdgcn_mfma_f32_16x16x32_bf16(av, b2, a2, 0, 0, 0);
    a3 = __builtin_amdgcn_mfma_f32_16x16x32_bf16(av, b3, a3, 0, 0, 0);
  }
  int col = l & 15, rb = m0 + wv * 16 + (l >> 4) * 4;
  f32x4 accs[4] = {a0, a1, a2, a3};
#pragma unroll
  for (int g = 0; g < 4; ++g) {
    int n = n0 + g * 16 + col;
    float bs = bias ? bias[n] : 0.0f;
#pragma unroll
    for (int i2 = 0; i2 < 4; ++i2)
      out[(size_t)(rb + i2) * N + n] = accs[g][i2] + bs;
  }
}

// ---------------------------------------------------------------- LSTM
// Decoupled chains: 32 L0 WGs (16 units) + 64 L1 WGs (8 units). Ring depth 8.
// All cross-WG h/flag traffic = agent-scope atomics (coherent point). RELAXED
// polls + one acquire fence on exit; producer: s_waitcnt vmcnt(0) + relaxed store.
#define L0WG 32
#define NWGT 96

DEVI short8 ald16(const u16* p) {
  union { unsigned long long q[2]; short8 v; } u;
  u.q[0] = __hip_atomic_load((unsigned long long*)p,       __ATOMIC_RELAXED, __HIP_MEMORY_SCOPE_AGENT);
  u.q[1] = __hip_atomic_load((unsigned long long*)(p + 4), __ATOMIC_RELAXED, __HIP_MEMORY_SCOPE_AGENT);
  return u.v;
}
DEVI void waitflags(const int* f0, const int* f1, int n0, int n1) {
  if (threadIdx.x < 64) {
    int l = threadIdx.x;
    for (;;) {
      int a = __hip_atomic_load((int*)(f0 + (l & 31) * 16), __ATOMIC_RELAXED, __HIP_MEMORY_SCOPE_AGENT);
      int b = __hip_atomic_load((int*)(f1 + l * 16),        __ATOMIC_RELAXED, __HIP_MEMORY_SCOPE_AGENT);
      if (__all(a >= n0 && b >= n1)) break;
      __builtin_amdgcn_s_sleep(1);
    }
    __builtin_amdgcn_fence(__ATOMIC_ACQUIRE, "agent");  // pin h-loads below poll
  }
  __syncthreads();
}
DEVI void postflag(int* slot, int val) {
  __syncthreads();
  if (threadIdx.x == 0) {
    asm volatile("s_waitcnt vmcnt(0)" ::: "memory");    // h-stores ack'd at L3
    __hip_atomic_store(slot, val, __ATOMIC_RELAXED, __HIP_MEMORY_SCOPE_AGENT);
  }
}
DEVI const u16* haddr(const u16* base, int slot, int k, int b) {
  return base + slot * 8192 + (k >> 4) * 256 + b * 16 + (k & 15);
}
DEVI void hstore(u16* base, int idx, u16 mine, int tid) {
  int other = __shfl_xor((int)mine, 1);
  if (!(tid & 1)) {
    uint32_t pkv = (uint32_t)mine | (((uint32_t)other & 0xffffu) << 16);
    __hip_atomic_store((uint32_t*)(base + idx), pkv, __ATOMIC_RELAXED, __HIP_MEMORY_SCOPE_AGENT);
  }
}

__global__ __launch_bounds__(256) void lstm_kernel(
    const float* __restrict__ Xg0,                 // [64][16][2048] (x@Wih0^T + bsum0)
    const u16* __restrict__ Whh0, const u16* __restrict__ Wih1, const u16* __restrict__ Whh1,
    const float* __restrict__ bsum1,
    u16* __restrict__ h0b, u16* __restrict__ h1b,  // [8][32][16][16] rings
    u16* __restrict__ Hdec,                        // [64][16][512] bf16
    int* __restrict__ flags0, int* __restrict__ flags1)
{
  __shared__ float red[16][256];
  const int bid = blockIdx.x, tid = threadIdx.x;
  const int wv = tid >> 6, l = tid & 63;
  const int lb = l & 15, kof = (l >> 4) * 8;
  const int drb = (l >> 4) * 4;

  if (bid < L0WG) {
    // ---------------- layer 0: units [16*bid, +16)
    const int be = tid >> 4, je = tid & 15, jg = (bid << 4) + je;
    short8 breg[16];
#pragma unroll
    for (int g = 0; g < 4; ++g) {
      const u16* bp = Whh0 + (size_t)(g * 512 + bid * 16 + lb) * 512 + wv * 128 + kof;
#pragma unroll
      for (int ks = 0; ks < 4; ++ks)
        breg[g * 4 + ks] = *(const short8*)(bp + ks * 32);
    }
    float c0 = 0.f;
    for (int t = 0; t < 64; ++t) {
      // prefetch Xg0 before the flag wait
      const float* xg = Xg0 + (size_t)((t << 4) + be) * 2048 + jg;
      float x0 = xg[0], x1 = xg[512], x2 = xg[1024], x3 = xg[1536];
      waitflags(flags0, flags1, t, (t > 7) ? (t - 7) : 0);
      const int rs = (t + 7) & 7;
      f32x4 g0 = {0.f,0.f,0.f,0.f}, g1 = g0, g2 = g0, g3 = g0;
#pragma unroll
      for (int ks = 0; ks < 4; ++ks) {
        int kk = wv * 128 + ks * 32 + kof;
        short8 av = ald16(haddr(h0b, rs, kk, lb));
        g0 = __builtin_amdgcn_mfma_f32_16x16x32_bf16(av, breg[0 * 4 + ks], g0, 0, 0, 0);
        g1 = __builtin_amdgcn_mfma_f32_16x16x32_bf16(av, breg[1 * 4 + ks], g1, 0, 0, 0);
        g2 = __builtin_amdgcn_mfma_f32_16x16x32_bf16(av, breg[2 * 4 + ks], g2, 0, 0, 0);
        g3 = __builtin_amdgcn_mfma_f32_16x16x32_bf16(av, breg[3 * 4 + ks], g3, 0, 0, 0);
      }
      f32x4 gs[4] = {g0, g1, g2, g3};
#pragma unroll
      for (int g = 0; g < 4; ++g)
#pragma unroll
        for (int i2 = 0; i2 < 4; ++i2)
          red[wv * 4 + g][(drb + i2) * 16 + lb] = gs[g][i2];
      __syncthreads();
      {
        float s0 = 0, s1 = 0, s2 = 0, s3 = 0;
#pragma unroll
        for (int v2 = 0; v2 < 4; ++v2) {
          s0 += red[v2 * 4 + 0][be * 16 + je]; s1 += red[v2 * 4 + 1][be * 16 + je];
          s2 += red[v2 * 4 + 2][be * 16 + je]; s3 += red[v2 * 4 + 3][be * 16 + je];
        }
        float gi = s0 + x0, gf = s1 + x1, gg = s2 + x2, go = s3 + x3;
        float I = sigm(gi), F = sigm(gf), G = tanh_c(gg), O = sigm(go);
        c0 = F * c0 + I * G;
        float h0 = O * tanh_c(c0);
        hstore(h0b, ((t & 7) * 32 + bid) * 256 + (tid & ~1), f2bf(h0), tid);
      }
      postflag(flags0 + bid * 16, t + 1);
    }
  } else {
    // ---------------- layer 1: units [8v, +8), v = bid-32
    const int v = bid - L0WG;
    const u16* base0 = (wv < 2) ? Wih1 : Whh1;
    const int kbase = (wv & 1) * 256;
    short8 breg[16];
#pragma unroll
    for (int tt = 0; tt < 2; ++tt) {
      int c = tt * 16 + lb, gate = c >> 3, du = c & 7;
      const u16* bp = base0 + (size_t)(gate * 512 + v * 8 + du) * 512 + kbase + kof;
#pragma unroll
      for (int ks = 0; ks < 8; ++ks)
        breg[tt * 8 + ks] = *(const short8*)(bp + ks * 32);
    }
    float bs0 = 0, bs1 = 0, bs2 = 0, bs3 = 0, c1 = 0.f;
    if (tid < 128) {
      int du = tid & 7, ju = v * 8 + du;
      bs0 = bsum1[ju]; bs1 = bsum1[512 + ju]; bs2 = bsum1[1024 + ju]; bs3 = bsum1[1536 + ju];
    }
    for (int t = 0; t < 64; ++t) {
      waitflags(flags0, flags1, t + 1, t);
      const u16* hsrc = (wv < 2) ? (h0b + (t & 7) * 8192) : (h1b + ((t + 7) & 7) * 8192);
      f32x4 g0 = {0.f,0.f,0.f,0.f}, g1 = g0;
#pragma unroll
      for (int ks = 0; ks < 8; ++ks) {
        int kk = kbase + ks * 32 + kof;
        short8 av = ald16(hsrc + (kk >> 4) * 256 + lb * 16 + (kk & 15));
        g0 = __builtin_amdgcn_mfma_f32_16x16x32_bf16(av, breg[0 * 8 + ks], g0, 0, 0, 0);
        g1 = __builtin_amdgcn_mfma_f32_16x16x32_bf16(av, breg[1 * 8 + ks], g1, 0, 0, 0);
      }
#pragma unroll
      for (int i2 = 0; i2 < 4; ++i2) {
        red[wv * 2 + 0][(drb + i2) * 16 + lb] = g0[i2];
        red[wv * 2 + 1][(drb + i2) * 16 + lb] = g1[i2];
      }
      __syncthreads();
      u16 hb = 0; int be = 0, ju = 0;
      if (tid < 128) {
        be = tid >> 3; int du = tid & 7; ju = v * 8 + du;
        float sg[4] = {bs0, bs1, bs2, bs3};
#pragma unroll
        for (int g = 0; g < 4; ++g) {
          int c = g * 8 + du, tt = c >> 4, cc = c & 15;
          float acc = 0.f;
#pragma unroll
          for (int w2 = 0; w2 < 4; ++w2) acc += red[w2 * 2 + tt][be * 16 + cc];
          sg[g] += acc;
        }
        float I = sigm(sg[0]), F = sigm(sg[1]), G = tanh_c(sg[2]), O = sigm(sg[3]);
        c1 = F * c1 + I * G;
        float h1v = O * tanh_c(c1);
        hb = f2bf(h1v);
        int idx = ((t & 7) * 32 + (ju >> 4)) * 256 + be * 16 + (ju & 15);
        hstore(h1b, idx & ~1, hb, tid);
      }
      postflag(flags1 + v * 16, t + 1);
      if (tid < 128) Hdec[(size_t)((t << 4) + be) * 512 + ju] = hb;  // off critical path
    }
  }
}

// ---------------------------------------------------------------- joint
// out[b][t][u][n] = tanh(enc_p[b,t,:]+dec_p[u,b,:]) @ W_out^T + b_out
// r8 geometry (proven 355us): 256 thr (2M x 2N waves), M=64 (4t x 16u), N=320.
// NEW: W staged via async global_load_lds (16B/lane DMA) -- no staging VGPRs,
// no W ds_writes -> ~76 VGPR -> 3 WGs/CU. e/d loads issued BEFORE the DMAs so
// the z-build's vmcnt wait doesn't drain them. XCD-swizzled blockIdx.
__global__ __launch_bounds__(256) void joint_kernel(
    const float* __restrict__ enc_p,   // [16*200][512]
    const float* __restrict__ dec_p,   // [64*16][512]  row = u*16+b
    const u16* __restrict__ Wshuf,     // [32 kc][20 tile][64 lane][8] bf16
    const float* __restrict__ boutp,   // [640]
    float* __restrict__ out)
{
  __shared__ int4 wlds[2][1280];  // 2 x 20KB: W chunk (2 kc x 10 tiles x 64 lanes)
  __shared__ int4 zlds[2][256];   // 2 x 4KB:  z chunk 64 rows x 32 k, frag-shuffled
  // bijective XCD swizzle (6400 % 8 == 0): groups the 8 WGs sharing (b,tb)
  // onto one XCD for enc_p L2 locality.
  int bid = ((int)blockIdx.x & 7) * 800 + ((int)blockIdx.x >> 3);
  int b = bid / 400, rem = bid % 400;
  int tb = rem / 8, rem2 = rem % 8;
  int ub = rem2 >> 1, nh = rem2 & 1;
  int tid = threadIdx.x, wv = tid >> 6, l = tid & 63;
  int mv = wv >> 1, nv = wv & 1;     // 2M x 2N
  int ln31 = l & 31, lh = l >> 5;
  const int tile0 = nv * 5;          // within this WG's 10-tile half
  f32x16 acc[5];
#pragma unroll
  for (int j = 0; j < 5; ++j) {
    float bv = boutp[nh * 320 + (tile0 + j) * 32 + ln31];
#pragma unroll
    for (int g = 0; g < 16; ++g) acc[j][g] = bv;
  }
  int zr = tid & 63, zg = tid >> 6;
  const float* er = enc_p + (size_t)(b * 200 + tb * 4 + (zr >> 4)) * 512 + zg * 8;
  const float* dr = dec_p + (size_t)((ub * 16 + (zr & 15)) * 16 + b) * 512 + zg * 8;
  const int zslot = ((zg >> 1) * 2 + (zr >> 5)) * 64 + ((zg & 1) << 5) + (zr & 31);
  const int4* gW = (const int4*)Wshuf;
  const int nhof = nh * 640;
  const int wvb = wv * 64;                    // wave-uniform LDS lane base
  const int s2g = (wv >= 2) ? 640 : 0;        // wave-uniform q=2 source bump

  // stage one W chunk (20KB) into wlds[buf] via 5 async DMAs
  auto stage_w = [&](int c, int buf) {
    const int4* src = gW + c * 2560 + nhof;
    gl16(src + tid,              &wlds[buf][wvb]);
    gl16(src + 256 + tid,        &wlds[buf][256 + wvb]);
    gl16(src + 512 + tid + s2g,  &wlds[buf][512 + wvb]);
    gl16(src + 1408 + tid,       &wlds[buf][768 + wvb]);
    gl16(src + 1664 + tid,       &wlds[buf][1024 + wvb]);
  };

  // ---- prologue: W(0) -> wlds[0] (DMA), z(0) -> zlds[0]
  {
    float4 e0 = *(const float4*)(er),     e1 = *(const float4*)(er + 4);
    float4 d0 = *(const float4*)(dr),     d1 = *(const float4*)(dr + 4);
    stage_w(0, 0);
    int4 pk;
    pk.x = (int)tj2(e0.x + d0.x, e0.y + d0.y);
    pk.y = (int)tj2(e0.z + d0.z, e0.w + d0.w);
    pk.z = (int)tj2(e1.x + d1.x, e1.y + d1.y);
    pk.w = (int)tj2(e1.z + d1.z, e1.w + d1.w);
    zlds[0][zslot] = pk;
    __syncthreads();
  }

  for (int c = 0; c < 16; ++c) {
    const int cur = c & 1, nxt = cur ^ 1;
    const bool pf = (c < 15);
    float4 e0, e1, d0, d1;
    if (pf) {
      // e/d loads FIRST (so their vmcnt wait doesn't drain the DMAs),
      // then the W(c+1) DMA into the other buffer; MFMAs hide both.
      int k0 = (c + 1) * 32;
      e0 = *(const float4*)(er + k0);     e1 = *(const float4*)(er + k0 + 4);
      d0 = *(const float4*)(dr + k0);     d1 = *(const float4*)(dr + k0 + 4);
      stage_w(c + 1, nxt);
    }
    // MFMA on chunk c
#pragma unroll
    for (int ks = 0; ks < 2; ++ks) {
      short8 aA = *(const short8*)&zlds[cur][(ks * 2 + mv) * 64 + l];
#pragma unroll
      for (int j = 0; j < 5; ++j) {
        short8 bw = *(const short8*)&wlds[cur][ks * 640 + (tile0 + j) * 64 + l];
        acc[j] = __builtin_amdgcn_mfma_f32_32x32x16_bf16(aA, bw, acc[j], 0, 0, 0);
      }
    }
    if (pf) {
      int4 pk;
      pk.x = (int)tj2(e0.x + d0.x, e0.y + d0.y);
      pk.y = (int)tj2(e0.z + d0.z, e0.w + d0.w);
      pk.z = (int)tj2(e1.x + d1.x, e1.y + d1.y);
      pk.w = (int)tj2(e1.z + d1.z, e1.w + d1.w);
      zlds[nxt][zslot] = pk;
    }
    __syncthreads();   // drains DMA (vmcnt) + z ds_write (lgkm) for chunk c+1
  }

  // epilogue: D[row][col]: col = lane&31, row = (g&3) + 8*(g>>2) + 4*(lane>>5)
#pragma unroll
  for (int j = 0; j < 5; ++j) {
    int n = nh * 320 + (tile0 + j) * 32 + ln31;
    if (n < 600) {
      int rbase = mv * 32 + 4 * lh;
#pragma unroll
      for (int g = 0; g < 16; ++g) {
        int r = rbase + (g & 3) + ((g >> 2) << 3);
        int tt = tb * 4 + (r >> 4), uu = ub * 16 + (r & 15);
        out[(size_t)((b * 200 + tt) * 64 + uu) * 600 + n] = acc[j][g];
      }
    }
  }
}

// ---------------------------------------------------------------- host
extern "C" void kernel_launch(void* const* d_in, const int* in_sizes, int n_in,
                              void* d_out, int out_size, void* d_ws, size_t ws_size,
                              hipStream_t stream) {
  const float* hs_pad = (const float*)d_in[0];
  const int*   ys     = (const int*)d_in[1];
  const float* embed  = (const float*)d_in[2];
  const float* W_ih0  = (const float*)d_in[3];
  const float* W_hh0  = (const float*)d_in[4];
  const float* b_ih0  = (const float*)d_in[5];
  const float* b_hh0  = (const float*)d_in[6];
  const float* W_ih1  = (const float*)d_in[7];
  const float* W_hh1  = (const float*)d_in[8];
  const float* b_ih1  = (const float*)d_in[9];
  const float* b_hh1  = (const float*)d_in[10];
  const float* W_enc  = (const float*)d_in[11];
  const float* b_enc  = (const float*)d_in[12];
  const float* W_dec  = (const float*)d_in[13];
  const float* W_out  = (const float*)d_in[14];
  const float* b_out  = (const float*)d_in[15];
  float* out = (float*)d_out;

  uint8_t* ws = (uint8_t*)d_ws;
  size_t off = 0;
  auto alloc = [&](size_t bytes) -> void* {
    void* p = ws + off;
    off = (off + bytes + 255) & ~(size_t)255;
    return p;
  };
  int* flags0   = (int*)alloc(2048);                     // 32 slots x 64B
  int* flags1   = (int*)alloc(4096);                     // 64 slots x 64B
  u16* h0buf    = (u16*)alloc(8 * 32 * 256 * 2);         // 128 KB ring (8 slots)
  u16* h1buf    = (u16*)alloc(8 * 32 * 256 * 2);         // 128 KB ring
  u16* Hdec     = (u16*)alloc(64 * 16 * 512 * 2);        // 1 MB
  float* Xg0    = (float*)alloc(1024 * 2048 * 4);        // 8 MB
  float* enc_p  = (float*)alloc(3200 * 512 * 4);         // 6.5 MB
  float* dec_p  = (float*)alloc(1024 * 512 * 4);         // 2 MB
  u16* Wih0b    = (u16*)alloc(2048 * 512 * 2);
  u16* Whh0b    = (u16*)alloc(2048 * 512 * 2);
  u16* Wih1b    = (u16*)alloc(2048 * 512 * 2);
  u16* Whh1b    = (u16*)alloc(2048 * 512 * 2);
  u16* Wencb    = (u16*)alloc(512 * 512 * 2);
  u16* Wdecb    = (u16*)alloc(512 * 512 * 2);
  u16* embedb   = (u16*)alloc(600 * 512 * 2);
  u16* hsb      = (u16*)alloc(3200 * 512 * 2);
  u16* Wshufb   = (u16*)alloc(32 * 20 * 64 * 8 * 2);
  float* bsum0  = (float*)alloc(2048 * 4);
  float* bsum1  = (float*)alloc(2048 * 4);
  float* boutp  = (float*)alloc(640 * 4);

  // zero flags + h rings (contiguous: 2048 + 4096 + 128K + 128K)
  (void)hipMemsetAsync(d_ws, 0, 2048 + 4096 + 131072 + 131072, stream);

  prep_kernel<<<2048, 256, 0, stream>>>(
      W_ih0, W_hh0, W_ih1, W_hh1, W_enc, W_dec, W_out, embed, hs_pad,
      b_ih0, b_hh0, b_ih1, b_hh1, b_out,
      Wih0b, Whh0b, Wih1b, Whh1b, Wencb, Wdecb, embedb, hsb, Wshufb,
      bsum0, bsum1, boutp);

  // Xg0 = embed[ys] @ W_ih0^T + (b_ih0 + b_hh0), rows m = u*16+b
  dim3 g1(16, 32);
  gemm_bf16<<<g1, 256, 0, stream>>>(embedb, Wih0b, ys, bsum0, Xg0, 2048, 1);
  // enc_p = hs @ W_enc^T + b_enc
  dim3 g2(50, 8);
  gemm_bf16<<<g2, 256, 0, stream>>>(hsb, Wencb, nullptr, b_enc, enc_p, 512, 0);
  // sequential 2-layer LSTM (decoupled chains, coherent atomics, light sync)
  lstm_kernel<<<NWGT, 256, 0, stream>>>(Xg0, Whh0b, Wih1b, Whh1b, bsum1,
                                        h0buf, h1buf, Hdec, flags0, flags1);
  // dec_p = Hdec @ W_dec^T
  dim3 g3(16, 8);
  gemm_bf16<<<g3, 256, 0, stream>>>(Hdec, Wdecb, nullptr, nullptr, dec_p, 512, 0);
  // big fused joint (r8 geometry + async W DMA + XCD swizzle)
  joint_kernel<<<6400, 256, 0, stream>>>(enc_p, dec_p, Wshufb, boutp, out);
}

// Round 11
// 604.884 us; speedup vs baseline: 1.2126x; 1.1115x over previous
//
#include <hip/hip_runtime.h>
#include <hip/hip_bf16.h>
#include <stdint.h>

#define DEVI __device__ __forceinline__

typedef unsigned short u16;
typedef __attribute__((ext_vector_type(8))) short short8;
typedef __attribute__((ext_vector_type(4))) float f32x4;
typedef __attribute__((ext_vector_type(16))) float f32x16;

DEVI u16 f2bf(float f) {
  union { float f; uint32_t u; } v; v.f = f;
  return (u16)((v.u + 0x7fffu + ((v.u >> 16) & 1u)) >> 16);
}
// cheap activations: v_rcp (1 ulp) instead of the 9-inst correctly-rounded div.
DEVI float tanh_c(float x) {
  float e = __expf(x + x);
  float r = __builtin_amdgcn_rcpf(e + 1.0f);
  return __builtin_fmaf(-2.0f, r, 1.0f);
}
DEVI float sigm(float x) { return __builtin_amdgcn_rcpf(1.0f + __expf(-x)); }
// two tanh -> packed bf16x2 (hardware v_cvt_pk_bf16_f32, RNE)
DEVI uint32_t tj2(float a, float b) {
  float ea = __expf(a + a), eb = __expf(b + b);
  float ta = __builtin_fmaf(-2.0f, __builtin_amdgcn_rcpf(ea + 1.0f), 1.0f);
  float tb = __builtin_fmaf(-2.0f, __builtin_amdgcn_rcpf(eb + 1.0f), 1.0f);
  union { __hip_bfloat162 h; uint32_t u; } cv;
  cv.h = __float22bfloat162_rn(make_float2(ta, tb));
  return cv.u;
}

// ---------------------------------------------------------------- prep
__global__ void prep_kernel(
    const float* __restrict__ W_ih0, const float* __restrict__ W_hh0,
    const float* __restrict__ W_ih1, const float* __restrict__ W_hh1,
    const float* __restrict__ W_enc, const float* __restrict__ W_dec,
    const float* __restrict__ W_out, const float* __restrict__ embed,
    const float* __restrict__ hs_pad,
    const float* __restrict__ b_ih0, const float* __restrict__ b_hh0,
    const float* __restrict__ b_ih1, const float* __restrict__ b_hh1,
    const float* __restrict__ b_out,
    u16* __restrict__ Wih0b, u16* __restrict__ Whh0b,
    u16* __restrict__ Wih1b, u16* __restrict__ Whh1b,
    u16* __restrict__ Wencb, u16* __restrict__ Wdecb,
    u16* __restrict__ embedb, u16* __restrict__ hsb,
    u16* __restrict__ Wshufb,
    float* __restrict__ bsum0, float* __restrict__ bsum1, float* __restrict__ boutp)
{
  const int c1 = 1048576, c2 = 2097152, c3 = 3145728, c4 = 4194304;
  const int c5 = 4456448, c6 = 4718592, c7 = 5025792, c8 = 6664192;
  const int c9 = 6991872, c10 = 6993920, c11 = 6995968, c12 = 6996608;
  for (int i = blockIdx.x * blockDim.x + threadIdx.x; i < c12; i += gridDim.x * blockDim.x) {
    if (i < c1)       Wih0b[i]      = f2bf(W_ih0[i]);
    else if (i < c2)  Whh0b[i - c1] = f2bf(W_hh0[i - c1]);
    else if (i < c3)  Wih1b[i - c2] = f2bf(W_ih1[i - c2]);
    else if (i < c4)  Whh1b[i - c3] = f2bf(W_hh1[i - c3]);
    else if (i < c5)  Wencb[i - c4] = f2bf(W_enc[i - c4]);
    else if (i < c6)  Wdecb[i - c5] = f2bf(W_dec[i - c5]);
    else if (i < c7)  embedb[i - c6] = f2bf(embed[i - c6]);
    else if (i < c8)  hsb[i - c7]   = f2bf(hs_pad[i - c7]);
    else if (i < c9) {
      // W_out pre-shuffled for 32x32x16 B-fragments: [32 kc][20 tile][64 lane][8]
      int e = i - c8;
      int kc = e / 10240, r = e % 10240;
      int tile = r >> 9, r2 = r & 511;
      int lane = r2 >> 3, ii = r2 & 7;
      int n = tile * 32 + (lane & 31);
      int k = kc * 16 + ((lane >> 5) << 3) + ii;
      Wshufb[e] = (n < 600) ? f2bf(W_out[n * 512 + k]) : (u16)0;
    }
    else if (i < c10) { int n = i - c9;  bsum0[n] = b_ih0[n] + b_hh0[n]; }
    else if (i < c11) { int n = i - c10; bsum1[n] = b_ih1[n] + b_hh1[n]; }
    else              { int n = i - c11; boutp[n] = (n < 600) ? b_out[n] : 0.0f; }
  }
}

// ------------------------------------------------- generic 64x64 MFMA GEMM
__global__ __launch_bounds__(256) void gemm_bf16(
    const u16* __restrict__ A, const u16* __restrict__ B,
    const int* __restrict__ ys, const float* __restrict__ bias,
    float* __restrict__ out, int N, int mode)
{
  int tid = threadIdx.x, wv = tid >> 6, l = tid & 63;
  int m0 = blockIdx.x * 64, n0 = blockIdx.y * 64;
  int row = m0 + wv * 16 + (l & 15);
  const u16* arow;
  if (mode == 1) { int uu = row >> 4, bb = row & 15; arow = A + (size_t)ys[bb * 64 + uu] * 512; }
  else           arow = A + (size_t)row * 512;
  int kof = (l >> 4) * 8;
  arow += kof;
  const u16* br = B + (size_t)(n0 + (l & 15)) * 512 + kof;
  f32x4 a0 = {0.f,0.f,0.f,0.f}, a1 = a0, a2 = a0, a3 = a0;
  for (int kk = 0; kk < 512; kk += 32) {
    short8 av = *(const short8*)(arow + kk);
    short8 b0 = *(const short8*)(br + kk);
    short8 b1 = *(const short8*)(br + 8192 + kk);
    short8 b2 = *(const short8*)(br + 16384 + kk);
    short8 b3 = *(const short8*)(br + 24576 + kk);
    a0 = __builtin_amdgcn_mfma_f32_16x16x32_bf16(av, b0, a0, 0, 0, 0);
    a1 = __builtin_amdgcn_mfma_f32_16x16x32_bf16(av, b1, a1, 0, 0, 0);
    a2 = __builtin_amdgcn_mfma_f32_16x16x32_bf16(av, b2, a2, 0, 0, 0);
    a3 = __builtin_amdgcn_mfma_f32_16x16x32_bf16(av, b3, a3, 0, 0, 0);
  }
  int col = l & 15, rb = m0 + wv * 16 + (l >> 4) * 4;
  f32x4 accs[4] = {a0, a1, a2, a3};
#pragma unroll
  for (int g = 0; g < 4; ++g) {
    int n = n0 + g * 16 + col;
    float bs = bias ? bias[n] : 0.0f;
#pragma unroll
    for (int i2 = 0; i2 < 4; ++i2)
      out[(size_t)(rb + i2) * N + n] = accs[g][i2] + bs;
  }
}

// ---------------------------------------------------------------- LSTM
// Decoupled chains: 32 L0 WGs (16 units) + 64 L1 WGs (8 units). Ring depth 8.
// All cross-WG h/flag traffic = agent-scope atomics (coherent point). RELAXED
// polls + one acquire fence on exit; producer: s_waitcnt vmcnt(0) + relaxed store.
#define L0WG 32
#define NWGT 96

DEVI short8 ald16(const u16* p) {
  union { unsigned long long q[2]; short8 v; } u;
  u.q[0] = __hip_atomic_load((unsigned long long*)p,       __ATOMIC_RELAXED, __HIP_MEMORY_SCOPE_AGENT);
  u.q[1] = __hip_atomic_load((unsigned long long*)(p + 4), __ATOMIC_RELAXED, __HIP_MEMORY_SCOPE_AGENT);
  return u.v;
}
DEVI void waitflags(const int* f0, const int* f1, int n0, int n1) {
  if (threadIdx.x < 64) {
    int l = threadIdx.x;
    for (;;) {
      int a = __hip_atomic_load((int*)(f0 + (l & 31) * 16), __ATOMIC_RELAXED, __HIP_MEMORY_SCOPE_AGENT);
      int b = __hip_atomic_load((int*)(f1 + l * 16),        __ATOMIC_RELAXED, __HIP_MEMORY_SCOPE_AGENT);
      if (__all(a >= n0 && b >= n1)) break;
      __builtin_amdgcn_s_sleep(1);
    }
    __builtin_amdgcn_fence(__ATOMIC_ACQUIRE, "agent");  // pin h-loads below poll
  }
  __syncthreads();
}
DEVI void postflag(int* slot, int val) {
  __syncthreads();
  if (threadIdx.x == 0) {
    asm volatile("s_waitcnt vmcnt(0)" ::: "memory");    // h-stores ack'd at L3
    __hip_atomic_store(slot, val, __ATOMIC_RELAXED, __HIP_MEMORY_SCOPE_AGENT);
  }
}
DEVI const u16* haddr(const u16* base, int slot, int k, int b) {
  return base + slot * 8192 + (k >> 4) * 256 + b * 16 + (k & 15);
}
DEVI void hstore(u16* base, int idx, u16 mine, int tid) {
  int other = __shfl_xor((int)mine, 1);
  if (!(tid & 1)) {
    uint32_t pkv = (uint32_t)mine | (((uint32_t)other & 0xffffu) << 16);
    __hip_atomic_store((uint32_t*)(base + idx), pkv, __ATOMIC_RELAXED, __HIP_MEMORY_SCOPE_AGENT);
  }
}

__global__ __launch_bounds__(256) void lstm_kernel(
    const float* __restrict__ Xg0,                 // [64][16][2048] (x@Wih0^T + bsum0)
    const u16* __restrict__ Whh0, const u16* __restrict__ Wih1, const u16* __restrict__ Whh1,
    const float* __restrict__ bsum1,
    u16* __restrict__ h0b, u16* __restrict__ h1b,  // [8][32][16][16] rings
    u16* __restrict__ Hdec,                        // [64][16][512] bf16
    int* __restrict__ flags0, int* __restrict__ flags1)
{
  __shared__ float red[16][256];
  const int bid = blockIdx.x, tid = threadIdx.x;
  const int wv = tid >> 6, l = tid & 63;
  const int lb = l & 15, kof = (l >> 4) * 8;
  const int drb = (l >> 4) * 4;

  if (bid < L0WG) {
    // ---------------- layer 0: units [16*bid, +16)
    const int be = tid >> 4, je = tid & 15, jg = (bid << 4) + je;
    short8 breg[16];
#pragma unroll
    for (int g = 0; g < 4; ++g) {
      const u16* bp = Whh0 + (size_t)(g * 512 + bid * 16 + lb) * 512 + wv * 128 + kof;
#pragma unroll
      for (int ks = 0; ks < 4; ++ks)
        breg[g * 4 + ks] = *(const short8*)(bp + ks * 32);
    }
    float c0 = 0.f;
    for (int t = 0; t < 64; ++t) {
      // prefetch Xg0 before the flag wait
      const float* xg = Xg0 + (size_t)((t << 4) + be) * 2048 + jg;
      float x0 = xg[0], x1 = xg[512], x2 = xg[1024], x3 = xg[1536];
      waitflags(flags0, flags1, t, (t > 7) ? (t - 7) : 0);
      const int rs = (t + 7) & 7;
      f32x4 g0 = {0.f,0.f,0.f,0.f}, g1 = g0, g2 = g0, g3 = g0;
#pragma unroll
      for (int ks = 0; ks < 4; ++ks) {
        int kk = wv * 128 + ks * 32 + kof;
        short8 av = ald16(haddr(h0b, rs, kk, lb));
        g0 = __builtin_amdgcn_mfma_f32_16x16x32_bf16(av, breg[0 * 4 + ks], g0, 0, 0, 0);
        g1 = __builtin_amdgcn_mfma_f32_16x16x32_bf16(av, breg[1 * 4 + ks], g1, 0, 0, 0);
        g2 = __builtin_amdgcn_mfma_f32_16x16x32_bf16(av, breg[2 * 4 + ks], g2, 0, 0, 0);
        g3 = __builtin_amdgcn_mfma_f32_16x16x32_bf16(av, breg[3 * 4 + ks], g3, 0, 0, 0);
      }
      f32x4 gs[4] = {g0, g1, g2, g3};
#pragma unroll
      for (int g = 0; g < 4; ++g)
#pragma unroll
        for (int i2 = 0; i2 < 4; ++i2)
          red[wv * 4 + g][(drb + i2) * 16 + lb] = gs[g][i2];
      __syncthreads();
      {
        float s0 = 0, s1 = 0, s2 = 0, s3 = 0;
#pragma unroll
        for (int v2 = 0; v2 < 4; ++v2) {
          s0 += red[v2 * 4 + 0][be * 16 + je]; s1 += red[v2 * 4 + 1][be * 16 + je];
          s2 += red[v2 * 4 + 2][be * 16 + je]; s3 += red[v2 * 4 + 3][be * 16 + je];
        }
        float gi = s0 + x0, gf = s1 + x1, gg = s2 + x2, go = s3 + x3;
        float I = sigm(gi), F = sigm(gf), G = tanh_c(gg), O = sigm(go);
        c0 = F * c0 + I * G;
        float h0 = O * tanh_c(c0);
        hstore(h0b, ((t & 7) * 32 + bid) * 256 + (tid & ~1), f2bf(h0), tid);
      }
      postflag(flags0 + bid * 16, t + 1);
    }
  } else {
    // ---------------- layer 1: units [8v, +8), v = bid-32
    const int v = bid - L0WG;
    const u16* base0 = (wv < 2) ? Wih1 : Whh1;
    const int kbase = (wv & 1) * 256;
    short8 breg[16];
#pragma unroll
    for (int tt = 0; tt < 2; ++tt) {
      int c = tt * 16 + lb, gate = c >> 3, du = c & 7;
      const u16* bp = base0 + (size_t)(gate * 512 + v * 8 + du) * 512 + kbase + kof;
#pragma unroll
      for (int ks = 0; ks < 8; ++ks)
        breg[tt * 8 + ks] = *(const short8*)(bp + ks * 32);
    }
    float bs0 = 0, bs1 = 0, bs2 = 0, bs3 = 0, c1 = 0.f;
    if (tid < 128) {
      int du = tid & 7, ju = v * 8 + du;
      bs0 = bsum1[ju]; bs1 = bsum1[512 + ju]; bs2 = bsum1[1024 + ju]; bs3 = bsum1[1536 + ju];
    }
    for (int t = 0; t < 64; ++t) {
      waitflags(flags0, flags1, t + 1, t);
      const u16* hsrc = (wv < 2) ? (h0b + (t & 7) * 8192) : (h1b + ((t + 7) & 7) * 8192);
      f32x4 g0 = {0.f,0.f,0.f,0.f}, g1 = g0;
#pragma unroll
      for (int ks = 0; ks < 8; ++ks) {
        int kk = kbase + ks * 32 + kof;
        short8 av = ald16(hsrc + (kk >> 4) * 256 + lb * 16 + (kk & 15));
        g0 = __builtin_amdgcn_mfma_f32_16x16x32_bf16(av, breg[0 * 8 + ks], g0, 0, 0, 0);
        g1 = __builtin_amdgcn_mfma_f32_16x16x32_bf16(av, breg[1 * 8 + ks], g1, 0, 0, 0);
      }
#pragma unroll
      for (int i2 = 0; i2 < 4; ++i2) {
        red[wv * 2 + 0][(drb + i2) * 16 + lb] = g0[i2];
        red[wv * 2 + 1][(drb + i2) * 16 + lb] = g1[i2];
      }
      __syncthreads();
      u16 hb = 0; int be = 0, ju = 0;
      if (tid < 128) {
        be = tid >> 3; int du = tid & 7; ju = v * 8 + du;
        float sg[4] = {bs0, bs1, bs2, bs3};
#pragma unroll
        for (int g = 0; g < 4; ++g) {
          int c = g * 8 + du, tt = c >> 4, cc = c & 15;
          float acc = 0.f;
#pragma unroll
          for (int w2 = 0; w2 < 4; ++w2) acc += red[w2 * 2 + tt][be * 16 + cc];
          sg[g] += acc;
        }
        float I = sigm(sg[0]), F = sigm(sg[1]), G = tanh_c(sg[2]), O = sigm(sg[3]);
        c1 = F * c1 + I * G;
        float h1v = O * tanh_c(c1);
        hb = f2bf(h1v);
        int idx = ((t & 7) * 32 + (ju >> 4)) * 256 + be * 16 + (ju & 15);
        hstore(h1b, idx & ~1, hb, tid);
      }
      postflag(flags1 + v * 16, t + 1);
      if (tid < 128) Hdec[(size_t)((t << 4) + be) * 512 + ju] = hb;  // off critical path
    }
  }
}

// ---------------------------------------------------------------- joint
// out[b][t][u][n] = tanh(enc_p[b,t,:]+dec_p[u,b,:]) @ W_out^T + b_out
// EXACT r8 structure (proven 355us): 256 thr (2M x 2N waves), M=64, N=320,
// W regs->LDS dbuf 2x20KB + z dbuf 2x4KB (48KB), 1 barrier/chunk.
// ONLY change vs r8: nontemporal epilogue stores (write-once output; keep L2
// for the W-chunk stream + enc_p/dec_p re-reads).
__global__ __launch_bounds__(256) void joint_kernel(
    const float* __restrict__ enc_p,   // [16*200][512]
    const float* __restrict__ dec_p,   // [64*16][512]  row = u*16+b
    const u16* __restrict__ Wshuf,     // [32 kc][20 tile][64 lane][8] bf16
    const float* __restrict__ boutp,   // [640]
    float* __restrict__ out)
{
  __shared__ int4 wlds[2][1280];  // 2 x 20KB: W chunk (2 kc x 10 tiles x 64 lanes)
  __shared__ int4 zlds[2][256];   // 2 x 4KB:  z chunk 64 rows x 32 k, frag-shuffled
  int bid = blockIdx.x;
  int b = bid / 400, rem = bid % 400;
  int tb = rem / 8, rem2 = rem % 8;
  int ub = rem2 >> 1, nh = rem2 & 1;
  int tid = threadIdx.x, wv = tid >> 6, l = tid & 63;
  int mv = wv >> 1, nv = wv & 1;     // 2M x 2N
  int ln31 = l & 31, lh = l >> 5;
  const int tile0 = nv * 5;          // within this WG's 10-tile half
  f32x16 acc[5];
#pragma unroll
  for (int j = 0; j < 5; ++j) {
    float bv = boutp[nh * 320 + (tile0 + j) * 32 + ln31];
#pragma unroll
    for (int g = 0; g < 16; ++g) acc[j][g] = bv;
  }
  int zr = tid & 63, zg = tid >> 6;
  const float* er = enc_p + (size_t)(b * 200 + tb * 4 + (zr >> 4)) * 512 + zg * 8;
  const float* dr = dec_p + (size_t)((ub * 16 + (zr & 15)) * 16 + b) * 512 + zg * 8;
  const int zslot = ((zg >> 1) * 2 + (zr >> 5)) * 64 + ((zg & 1) << 5) + (zr & 31);
  const int4* gW = (const int4*)Wshuf;
  const int nhof = nh * 640;
  // per-chunk W slice (2 kc x 10 tiles): local L in [0,1280); global idx =
  // chunkbase + nhof + L + (L>=640)*640
  const int L0 = tid, L1 = 256 + tid, L2 = 512 + tid + ((tid >= 128) ? 640 : 0),
            L3 = 1408 + tid, L4 = 1664 + tid;
  const int S2 = 512 + tid;  // LDS slot for the q=2 load

  // ---- prologue: W(0) -> wlds[0], z(0) -> zlds[0]
  {
    int4 w0 = gW[nhof + L0], w1 = gW[nhof + L1], w2 = gW[nhof + L2],
         w3 = gW[nhof + L3], w4 = gW[nhof + L4];
    float4 e0 = *(const float4*)(er),     e1 = *(const float4*)(er + 4);
    float4 d0 = *(const float4*)(dr),     d1 = *(const float4*)(dr + 4);
    int4 pk;
    pk.x = (int)tj2(e0.x + d0.x, e0.y + d0.y);
    pk.y = (int)tj2(e0.z + d0.z, e0.w + d0.w);
    pk.z = (int)tj2(e1.x + d1.x, e1.y + d1.y);
    pk.w = (int)tj2(e1.z + d1.z, e1.w + d1.w);
    zlds[0][zslot] = pk;
    wlds[0][tid] = w0; wlds[0][256 + tid] = w1; wlds[0][S2] = w2;
    wlds[0][768 + tid] = w3; wlds[0][1024 + tid] = w4;
    __syncthreads();
  }

  for (int c = 0; c < 16; ++c) {
    const int cur = c & 1, nxt = cur ^ 1;
    const bool pf = (c < 15);
    int4 w0, w1, w2, w3, w4;
    float4 e0, e1, d0, d1;
    if (pf) {
      // issue next-chunk loads early; MFMAs below + co-resident WGs hide latency
      const int cb = (c + 1) * 2560 + nhof;
      w0 = gW[cb + L0]; w1 = gW[cb + L1]; w2 = gW[cb + L2];
      w3 = gW[cb + L3]; w4 = gW[cb + L4];
      int k0 = (c + 1) * 32;
      e0 = *(const float4*)(er + k0);     e1 = *(const float4*)(er + k0 + 4);
      d0 = *(const float4*)(dr + k0);     d1 = *(const float4*)(dr + k0 + 4);
    }
    // MFMA on chunk c
#pragma unroll
    for (int ks = 0; ks < 2; ++ks) {
      short8 aA = *(const short8*)&zlds[cur][(ks * 2 + mv) * 64 + l];
#pragma unroll
      for (int j = 0; j < 5; ++j) {
        short8 bw = *(const short8*)&wlds[cur][ks * 640 + (tile0 + j) * 64 + l];
        acc[j] = __builtin_amdgcn_mfma_f32_32x32x16_bf16(aA, bw, acc[j], 0, 0, 0);
      }
    }
    if (pf) {
      // write next chunk into the other buffers, then ONE barrier
      wlds[nxt][tid] = w0; wlds[nxt][256 + tid] = w1; wlds[nxt][S2] = w2;
      wlds[nxt][768 + tid] = w3; wlds[nxt][1024 + tid] = w4;
      int4 pk;
      pk.x = (int)tj2(e0.x + d0.x, e0.y + d0.y);
      pk.y = (int)tj2(e0.z + d0.z, e0.w + d0.w);
      pk.z = (int)tj2(e1.x + d1.x, e1.y + d1.y);
      pk.w = (int)tj2(e1.z + d1.z, e1.w + d1.w);
      zlds[nxt][zslot] = pk;
    }
    __syncthreads();
  }

  // epilogue: D[row][col]: col = lane&31, row = (g&3) + 8*(g>>2) + 4*(lane>>5)
  // nontemporal: output is write-once, never re-read -> don't evict L2 working set
#pragma unroll
  for (int j = 0; j < 5; ++j) {
    int n = nh * 320 + (tile0 + j) * 32 + ln31;
    if (n < 600) {
      int rbase = mv * 32 + 4 * lh;
#pragma unroll
      for (int g = 0; g < 16; ++g) {
        int r = rbase + (g & 3) + ((g >> 2) << 3);
        int tt = tb * 4 + (r >> 4), uu = ub * 16 + (r & 15);
        __builtin_nontemporal_store(
            acc[j][g], &out[(size_t)((b * 200 + tt) * 64 + uu) * 600 + n]);
      }
    }
  }
}

// ---------------------------------------------------------------- host
extern "C" void kernel_launch(void* const* d_in, const int* in_sizes, int n_in,
                              void* d_out, int out_size, void* d_ws, size_t ws_size,
                              hipStream_t stream) {
  const float* hs_pad = (const float*)d_in[0];
  const int*   ys     = (const int*)d_in[1];
  const float* embed  = (const float*)d_in[2];
  const float* W_ih0  = (const float*)d_in[3];
  const float* W_hh0  = (const float*)d_in[4];
  const float* b_ih0  = (const float*)d_in[5];
  const float* b_hh0  = (const float*)d_in[6];
  const float* W_ih1  = (const float*)d_in[7];
  const float* W_hh1  = (const float*)d_in[8];
  const float* b_ih1  = (const float*)d_in[9];
  const float* b_hh1  = (const float*)d_in[10];
  const float* W_enc  = (const float*)d_in[11];
  const float* b_enc  = (const float*)d_in[12];
  const float* W_dec  = (const float*)d_in[13];
  const float* W_out  = (const float*)d_in[14];
  const float* b_out  = (const float*)d_in[15];
  float* out = (float*)d_out;

  uint8_t* ws = (uint8_t*)d_ws;
  size_t off = 0;
  auto alloc = [&](size_t bytes) -> void* {
    void* p = ws + off;
    off = (off + bytes + 255) & ~(size_t)255;
    return p;
  };
  int* flags0   = (int*)alloc(2048);                     // 32 slots x 64B
  int* flags1   = (int*)alloc(4096);                     // 64 slots x 64B
  u16* h0buf    = (u16*)alloc(8 * 32 * 256 * 2);         // 128 KB ring (8 slots)
  u16* h1buf    = (u16*)alloc(8 * 32 * 256 * 2);         // 128 KB ring
  u16* Hdec     = (u16*)alloc(64 * 16 * 512 * 2);        // 1 MB
  float* Xg0    = (float*)alloc(1024 * 2048 * 4);        // 8 MB
  float* enc_p  = (float*)alloc(3200 * 512 * 4);         // 6.5 MB
  float* dec_p  = (float*)alloc(1024 * 512 * 4);         // 2 MB
  u16* Wih0b    = (u16*)alloc(2048 * 512 * 2);
  u16* Whh0b    = (u16*)alloc(2048 * 512 * 2);
  u16* Wih1b    = (u16*)alloc(2048 * 512 * 2);
  u16* Whh1b    = (u16*)alloc(2048 * 512 * 2);
  u16* Wencb    = (u16*)alloc(512 * 512 * 2);
  u16* Wdecb    = (u16*)alloc(512 * 512 * 2);
  u16* embedb   = (u16*)alloc(600 * 512 * 2);
  u16* hsb      = (u16*)alloc(3200 * 512 * 2);
  u16* Wshufb   = (u16*)alloc(32 * 20 * 64 * 8 * 2);
  float* bsum0  = (float*)alloc(2048 * 4);
  float* bsum1  = (float*)alloc(2048 * 4);
  float* boutp  = (float*)alloc(640 * 4);

  // zero flags + h rings (contiguous: 2048 + 4096 + 128K + 128K)
  (void)hipMemsetAsync(d_ws, 0, 2048 + 4096 + 131072 + 131072, stream);

  prep_kernel<<<2048, 256, 0, stream>>>(
      W_ih0, W_hh0, W_ih1, W_hh1, W_enc, W_dec, W_out, embed, hs_pad,
      b_ih0, b_hh0, b_ih1, b_hh1, b_out,
      Wih0b, Whh0b, Wih1b, Whh1b, Wencb, Wdecb, embedb, hsb, Wshufb,
      bsum0, bsum1, boutp);

  // Xg0 = embed[ys] @ W_ih0^T + (b_ih0 + b_hh0), rows m = u*16+b
  dim3 g1(16, 32);
  gemm_bf16<<<g1, 256, 0, stream>>>(embedb, Wih0b, ys, bsum0, Xg0, 2048, 1);
  // enc_p = hs @ W_enc^T + b_enc
  dim3 g2(50, 8);
  gemm_bf16<<<g2, 256, 0, stream>>>(hsb, Wencb, nullptr, b_enc, enc_p, 512, 0);
  // sequential 2-layer LSTM (decoupled chains, coherent atomics, light sync)
  lstm_kernel<<<NWGT, 256, 0, stream>>>(Xg0, Whh0b, Wih1b, Whh1b, bsum1,
                                        h0buf, h1buf, Hdec, flags0, flags1);
  // dec_p = Hdec @ W_dec^T
  dim3 g3(16, 8);
  gemm_bf16<<<g3, 256, 0, stream>>>(Hdec, Wdecb, nullptr, nullptr, dec_p, 512, 0);
  // big fused joint (exact r8 geometry + NT epilogue stores)
  joint_kernel<<<6400, 256, 0, stream>>>(enc_p, dec_p, Wshufb, boutp, out);
}